// Round 4
// baseline (782.194 us; speedup 1.0000x reference)
//
#include <hip/hip_runtime.h>

#define N_NODES 100000
#define N_EDGES 1600000
#define F 64

#define NBKT 391                 // coarse buckets = ceil(N/256), bucket = dst>>8
#define ABLK 256                 // blocks in bucket count/scatter passes
#define ECHUNK (N_EDGES / ABLK)  // 6250 edges per block (exact)
#define M_CNT (NBKT * ABLK)      // 100096-entry count matrix, bucket-major
#define S2C 512                  // scan chunk
#define S2B ((M_CNT + S2C - 1) / S2C)  // 196 scan blocks
#define CAP_D 6144               // LDS edge staging cap in bucket_csr (mean 4092)
#define RBLK 512                 // reduce1 grid

// ---- CSR build: atomic-free two-level counting sort by dst ----

// Pass A: per-block LDS histogram of coarse buckets (dst>>8).
__global__ void bucket_count_kernel(const int* __restrict__ dst,
                                    int* __restrict__ cnt) {
    __shared__ int hist[NBKT];
    for (int i = threadIdx.x; i < NBKT; i += 256) hist[i] = 0;
    __syncthreads();
    int base = blockIdx.x * ECHUNK;
    for (int i = threadIdx.x; i < ECHUNK; i += 256)
        atomicAdd(&hist[dst[base + i] >> 8], 1);
    __syncthreads();
    for (int i = threadIdx.x; i < NBKT; i += 256)
        cnt[i * ABLK + blockIdx.x] = hist[i];
}

// Exclusive scan of cnt[M_CNT]: 3-phase (block sums -> scan sums -> write).
__global__ void s_bsum(const int* __restrict__ a, int n, int* __restrict__ bsum) {
    __shared__ int red[256];
    int base = blockIdx.x * S2C;
    int i0 = base + threadIdx.x, i1 = i0 + 256;
    int v = 0;
    if (i0 < n) v += a[i0];
    if (i1 < n) v += a[i1];
    red[threadIdx.x] = v;
    __syncthreads();
    for (int off = 128; off > 0; off >>= 1) {
        if (threadIdx.x < off) red[threadIdx.x] += red[threadIdx.x + off];
        __syncthreads();
    }
    if (threadIdx.x == 0) bsum[blockIdx.x] = red[0];
}

__global__ void s_bscan(const int* __restrict__ bsum, int nb, int* __restrict__ boff) {
    __shared__ int s[256];
    int tid = threadIdx.x;
    int v = (tid < nb) ? bsum[tid] : 0;
    s[tid] = v;
    __syncthreads();
    for (int off = 1; off < 256; off <<= 1) {
        int t = (tid >= off) ? s[tid - off] : 0;
        __syncthreads();
        s[tid] += t;
        __syncthreads();
    }
    if (tid < nb) boff[tid] = s[tid] - v;  // exclusive
}

__global__ void s_scan_write(const int* __restrict__ a, int n,
                             const int* __restrict__ boff, int* __restrict__ off) {
    __shared__ int s[S2C];
    int base = blockIdx.x * S2C;
    int tid = threadIdx.x;
    int i0 = base + tid, i1 = i0 + 256;
    int v0 = (i0 < n) ? a[i0] : 0;
    int v1 = (i1 < n) ? a[i1] : 0;
    s[tid] = v0;
    s[tid + 256] = v1;
    __syncthreads();
    for (int o = 1; o < S2C; o <<= 1) {
        int x0 = (tid >= o) ? s[tid - o] : 0;
        int x1 = (tid + 256 >= o) ? s[tid + 256 - o] : 0;
        __syncthreads();
        s[tid] += x0;
        s[tid + 256] += x1;
        __syncthreads();
    }
    int b0 = boff[blockIdx.x];
    if (i0 < n) off[i0] = b0 + s[tid] - v0;      // exclusive
    if (i1 < n) off[i1] = b0 + s[tid + 256] - v1;
}

// Pass C: place (dst,src) into bucket-ordered ebuf. LDS cursors seeded from
// the scanned per-(bucket,block) offsets -> plain global stores, no atomics.
__global__ void bucket_scatter_kernel(const int* __restrict__ edges,
                                      const int* __restrict__ off,
                                      unsigned long long* __restrict__ ebuf) {
    __shared__ int cur[NBKT];
    for (int i = threadIdx.x; i < NBKT; i += 256)
        cur[i] = off[i * ABLK + blockIdx.x];
    __syncthreads();
    int base = blockIdx.x * ECHUNK;
    for (int i = threadIdx.x; i < ECHUNK; i += 256) {
        int s = edges[base + i];
        int d = edges[N_EDGES + base + i];
        int p = atomicAdd(&cur[d >> 8], 1);  // LDS atomic only
        ebuf[p] = ((unsigned long long)(unsigned)d << 32) | (unsigned)s;
    }
}

// Pass D: one block per bucket. Stage edges in LDS, count the bucket's 256
// local nodes (dst&255), in-block scan -> row_ptr + fully grouped col.
__global__ void bucket_csr_kernel(const unsigned long long* __restrict__ ebuf,
                                  const int* __restrict__ off,
                                  int* __restrict__ row_ptr,
                                  int* __restrict__ col) {
    __shared__ unsigned long long eb[CAP_D];
    __shared__ int hist[256];
    __shared__ int sc[256];
    __shared__ int cur[256];
    const int b = blockIdx.x;
    const int tid = threadIdx.x;
    const int base = off[b * ABLK];
    const int end = (b == NBKT - 1) ? N_EDGES : off[(b + 1) * ABLK];
    const int count = end - base;
    hist[tid] = 0;
    __syncthreads();
    const bool inlds = (count <= CAP_D);  // mean 4092, cap 6144; global fallback
    for (int i = tid; i < count; i += 256) {
        unsigned long long ed = ebuf[base + i];
        if (inlds) eb[i] = ed;
        atomicAdd(&hist[(int)(ed >> 32) & 255], 1);
    }
    __syncthreads();
    int v = hist[tid];
    sc[tid] = v;
    __syncthreads();
    for (int o = 1; o < 256; o <<= 1) {
        int t = (tid >= o) ? sc[tid - o] : 0;
        __syncthreads();
        sc[tid] += t;
        __syncthreads();
    }
    int ex = sc[tid] - v;  // exclusive
    cur[tid] = ex;
    int node = b * 256 + tid;
    if (node <= N_NODES) row_ptr[node] = base + ex;  // covers row_ptr[N]==E too
    __syncthreads();
    for (int i = tid; i < count; i += 256) {
        unsigned long long ed = inlds ? eb[i] : ebuf[base + i];
        int local = (int)(ed >> 32) & 255;
        int p = atomicAdd(&cur[local], 1);  // LDS atomic only
        col[base + p] = (int)(unsigned)ed;
    }
}

// ---- per-layer compute ----

// Atomic-free pull gather: wave-per-node, lane = feature.
__global__ void gather_kernel(const float* __restrict__ feat,
                              const int* __restrict__ row_ptr,
                              const int* __restrict__ col,
                              float* __restrict__ aggr) {
    int node = blockIdx.x * 4 + (threadIdx.x >> 6);
    int f = threadIdx.x & 63;
    if (node >= N_NODES) return;
    int beg = row_ptr[node];
    int end = row_ptr[node + 1];
    float acc = 0.f;
    int e = beg;
    for (; e + 3 < end; e += 4) {
        int s0 = col[e];
        int s1 = col[e + 1];
        int s2 = col[e + 2];
        int s3 = col[e + 3];
        float v0 = feat[(size_t)s0 * F + f];
        float v1 = feat[(size_t)s1 * F + f];
        float v2 = feat[(size_t)s2 * F + f];
        float v3 = feat[(size_t)s3 * F + f];
        acc += v0 + v1 + v2 + v3;
    }
    for (; e < end; e++) acc += feat[(size_t)col[e] * F + f];
    aggr[(size_t)node * F + f] = acc;
}

// Fused per-node transform: out = [relu](aggr @ w_rel + b_rel + x @ w_root)
// Row-local per block => out may alias xin (in-place) safely.
__global__ void transform_kernel(const float* __restrict__ aggr,
                                 const float* __restrict__ xin,
                                 const float* __restrict__ w_rel,
                                 const float* __restrict__ b_rel,
                                 const float* __restrict__ w_root,
                                 float* __restrict__ out,
                                 const int do_relu) {
    __shared__ float sA[64 * F];
    __shared__ float sX[64 * F];
    const int node0 = blockIdx.x * 64;
    float4* s4A = (float4*)sA;
    float4* s4X = (float4*)sX;
    const float4* gA = (const float4*)(aggr + (size_t)node0 * F);
    const float4* gX = (const float4*)(xin + (size_t)node0 * F);
    for (int k = threadIdx.x; k < 64 * F / 4; k += 256) {
        int node = node0 + (k >> 4);
        float4 a = make_float4(0.f, 0.f, 0.f, 0.f);
        float4 x = a;
        if (node < N_NODES) { a = gA[k]; x = gX[k]; }
        s4A[k] = a;
        s4X[k] = x;
    }
    __syncthreads();

    const int fp = threadIdx.x & 63;
    const int grp = threadIdx.x >> 6;
    float acc[16];
    const float bias = b_rel[fp];
#pragma unroll
    for (int k = 0; k < 16; k++) acc[k] = bias;

    for (int f = 0; f < F; f += 4) {
        float wr0 = w_rel[(f + 0) * F + fp];
        float wr1 = w_rel[(f + 1) * F + fp];
        float wr2 = w_rel[(f + 2) * F + fp];
        float wr3 = w_rel[(f + 3) * F + fp];
        float wo0 = w_root[(f + 0) * F + fp];
        float wo1 = w_root[(f + 1) * F + fp];
        float wo2 = w_root[(f + 2) * F + fp];
        float wo3 = w_root[(f + 3) * F + fp];
#pragma unroll
        for (int k = 0; k < 16; k++) {
            int n = grp * 16 + k;
            float4 a = *(const float4*)&sA[n * F + f];
            float4 x = *(const float4*)&sX[n * F + f];
            acc[k] += a.x * wr0 + a.y * wr1 + a.z * wr2 + a.w * wr3
                    + x.x * wo0 + x.y * wo1 + x.z * wo2 + x.w * wo3;
        }
    }
#pragma unroll
    for (int k = 0; k < 16; k++) {
        int n = grp * 16 + k;
        int node = node0 + n;
        if (node < N_NODES) {
            float v = acc[k];
            if (do_relu) v = fmaxf(v, 0.0f);
            out[(size_t)node * F + fp] = v;
        }
    }
}

// ---- layer 3 collapsed: S1 = sum_e h2[src(e)], S2 = sum_i h2[i] ----
// Two-stage partials (no global atomic contention on 2 cache lines).
__global__ void reduce1_kernel(const float* __restrict__ h,
                               const int* __restrict__ src,
                               float* __restrict__ partial) {
    __shared__ float s1[256], s2[256];
    int f = threadIdx.x & 63;
    int gw = blockIdx.x * 4 + (threadIdx.x >> 6);
    int nw = gridDim.x * 4;
    float a1 = 0.f, a2 = 0.f;
    for (int e = gw; e < N_EDGES; e += nw)
        a1 += h[(size_t)src[e] * F + f];
    for (int i = gw; i < N_NODES; i += nw)
        a2 += h[(size_t)i * F + f];
    s1[threadIdx.x] = a1;
    s2[threadIdx.x] = a2;
    __syncthreads();
    if (threadIdx.x < 64) {
        float t1 = s1[f] + s1[64 + f] + s1[128 + f] + s1[192 + f];
        float t2 = s2[f] + s2[64 + f] + s2[128 + f] + s2[192 + f];
        partial[blockIdx.x * 128 + f] = t1;
        partial[blockIdx.x * 128 + 64 + f] = t2;
    }
}

// out = (S1 . w_rel3 + S2 . w_root3)/N + b3
__global__ void final_reduce_kernel(const float* __restrict__ partial,
                                    const float* __restrict__ w_rel3,
                                    const float* __restrict__ b_rel3,
                                    const float* __restrict__ w_root3,
                                    float* __restrict__ out) {
    __shared__ float sS[128];
    int t = threadIdx.x;  // 128 threads
    float s = 0.f;
    for (int k = 0; k < RBLK; k++) s += partial[k * 128 + t];
    sS[t] = s;
    __syncthreads();
    if (t < 64) {  // wave 0
        float v = sS[t] * w_rel3[t] + sS[64 + t] * w_root3[t];
        for (int off = 32; off > 0; off >>= 1) v += __shfl_down(v, off);
        if (t == 0) out[0] = v * (1.0f / (float)N_NODES) + b_rel3[0];
    }
}

extern "C" void kernel_launch(void* const* d_in, const int* in_sizes, int n_in,
                              void* d_out, int out_size, void* d_ws, size_t ws_size,
                              hipStream_t stream) {
    const float* x       = (const float*)d_in[0];
    const int*   edges   = (const int*)d_in[1];   // [2, E]: src row then dst row
    const float* w_rel1  = (const float*)d_in[2];
    const float* b_rel1  = (const float*)d_in[3];
    const float* w_root1 = (const float*)d_in[4];
    const float* w_rel2  = (const float*)d_in[5];
    const float* b_rel2  = (const float*)d_in[6];
    const float* w_root2 = (const float*)d_in[7];
    const float* w_rel3  = (const float*)d_in[8];
    const float* b_rel3  = (const float*)d_in[9];
    const float* w_root3 = (const float*)d_in[10];
    float* out = (float*)d_out;

    const size_t nf = (size_t)N_NODES * F;
    float* aggr    = (float*)d_ws;                 // 25.6 MB
    float* h1      = aggr + nf;                    // 25.6 MB (layer2 in-place)
    int*   row_ptr = (int*)(h1 + nf);              // 400 KB
    int*   col     = row_ptr + N_NODES + 1;        // 6.4 MB
    int*   cnt     = col + N_EDGES;                // 400 KB
    int*   off     = cnt + M_CNT;                  // 400 KB
    int*   bsum2   = off + M_CNT;                  // ~1 KB
    int*   boff2   = bsum2 + S2B;                  // ~1 KB
    float* partial = (float*)(boff2 + S2B);        // 256 KB
    // ebuf overlays aggr: dead before the first gather, 12.8 MB <= 25.6 MB
    unsigned long long* ebuf = (unsigned long long*)aggr;

    const int* dst_row = edges + N_EDGES;

    // CSR build (atomic-free counting sort; every buffer fully written -> no memsets)
    bucket_count_kernel<<<ABLK, 256, 0, stream>>>(dst_row, cnt);
    s_bsum<<<S2B, 256, 0, stream>>>(cnt, M_CNT, bsum2);
    s_bscan<<<1, 256, 0, stream>>>(bsum2, S2B, boff2);
    s_scan_write<<<S2B, 256, 0, stream>>>(cnt, M_CNT, boff2, off);
    bucket_scatter_kernel<<<ABLK, 256, 0, stream>>>(edges, off, ebuf);
    bucket_csr_kernel<<<NBKT, 256, 0, stream>>>(ebuf, off, row_ptr, col);

    const int gather_blocks = (N_NODES + 3) / 4;

    // layer 1 (gather overwrites the ebuf overlay after bucket_csr is done)
    gather_kernel<<<gather_blocks, 256, 0, stream>>>(x, row_ptr, col, aggr);
    transform_kernel<<<(N_NODES + 63) / 64, 256, 0, stream>>>(aggr, x, w_rel1, b_rel1, w_root1, h1, 1);

    // layer 2 (in-place)
    gather_kernel<<<gather_blocks, 256, 0, stream>>>(h1, row_ptr, col, aggr);
    transform_kernel<<<(N_NODES + 63) / 64, 256, 0, stream>>>(aggr, h1, w_rel2, b_rel2, w_root2, h1, 1);

    // layer 3 collapsed to reductions
    reduce1_kernel<<<RBLK, 256, 0, stream>>>(h1, edges, partial);
    final_reduce_kernel<<<1, 128, 0, stream>>>(partial, w_rel3, b_rel3, w_root3, out);
}

// Round 5
// 447.580 us; speedup vs baseline: 1.7476x; 1.7476x over previous
//
#include <hip/hip_runtime.h>

#define N_NODES 100000
#define N_EDGES 1600000
#define F 64

#define NBKT 391                 // coarse buckets = ceil(N/256), bucket = id>>8
#define ABLK 256                 // blocks in bucket count/scatter passes
#define ECHUNK (N_EDGES / ABLK)  // 6250 edges per block (exact)
#define M_CNT (NBKT * ABLK)      // 100096-entry count matrix, bucket-major
#define S2C 512                  // scan chunk
#define S2B ((M_CNT + S2C - 1) / S2C)  // 196 scan blocks
#define CAP_D 6144               // LDS edge staging cap in bucket_csr (mean 4092)
#define TBLK ((N_NODES + 63) / 64)     // 1563 transform blocks

// ---- counting-sort building blocks (used for dst-CSR and src-histogram) ----

// Per-block LDS histogram of coarse buckets (key>>8).
__global__ void bucket_count_kernel(const int* __restrict__ key,
                                    int* __restrict__ cnt) {
    __shared__ int hist[NBKT];
    for (int i = threadIdx.x; i < NBKT; i += 256) hist[i] = 0;
    __syncthreads();
    int base = blockIdx.x * ECHUNK;
    for (int i = threadIdx.x; i < ECHUNK; i += 256)
        atomicAdd(&hist[key[base + i] >> 8], 1);
    __syncthreads();
    for (int i = threadIdx.x; i < NBKT; i += 256)
        cnt[i * ABLK + blockIdx.x] = hist[i];
}

// Exclusive scan of cnt[M_CNT]: 3-phase (block sums -> scan sums -> write).
__global__ void s_bsum(const int* __restrict__ a, int n, int* __restrict__ bsum) {
    __shared__ int red[256];
    int base = blockIdx.x * S2C;
    int i0 = base + threadIdx.x, i1 = i0 + 256;
    int v = 0;
    if (i0 < n) v += a[i0];
    if (i1 < n) v += a[i1];
    red[threadIdx.x] = v;
    __syncthreads();
    for (int off = 128; off > 0; off >>= 1) {
        if (threadIdx.x < off) red[threadIdx.x] += red[threadIdx.x + off];
        __syncthreads();
    }
    if (threadIdx.x == 0) bsum[blockIdx.x] = red[0];
}

__global__ void s_bscan(const int* __restrict__ bsum, int nb, int* __restrict__ boff) {
    __shared__ int s[256];
    int tid = threadIdx.x;
    int v = (tid < nb) ? bsum[tid] : 0;
    s[tid] = v;
    __syncthreads();
    for (int off = 1; off < 256; off <<= 1) {
        int t = (tid >= off) ? s[tid - off] : 0;
        __syncthreads();
        s[tid] += t;
        __syncthreads();
    }
    if (tid < nb) boff[tid] = s[tid] - v;  // exclusive
}

__global__ void s_scan_write(const int* __restrict__ a, int n,
                             const int* __restrict__ boff, int* __restrict__ off) {
    __shared__ int s[S2C];
    int base = blockIdx.x * S2C;
    int tid = threadIdx.x;
    int i0 = base + tid, i1 = i0 + 256;
    int v0 = (i0 < n) ? a[i0] : 0;
    int v1 = (i1 < n) ? a[i1] : 0;
    s[tid] = v0;
    s[tid + 256] = v1;
    __syncthreads();
    for (int o = 1; o < S2C; o <<= 1) {
        int x0 = (tid >= o) ? s[tid - o] : 0;
        int x1 = (tid + 256 >= o) ? s[tid + 256 - o] : 0;
        __syncthreads();
        s[tid] += x0;
        s[tid + 256] += x1;
        __syncthreads();
    }
    int b0 = boff[blockIdx.x];
    if (i0 < n) off[i0] = b0 + s[tid] - v0;      // exclusive
    if (i1 < n) off[i1] = b0 + s[tid + 256] - v1;
}

// dst pass C: place (dst,src) into bucket-ordered ebuf. LDS cursors seeded
// from scanned per-(bucket,block) offsets -> plain global stores, no atomics.
__global__ void bucket_scatter_kernel(const int* __restrict__ edges,
                                      const int* __restrict__ off,
                                      unsigned long long* __restrict__ ebuf) {
    __shared__ int cur[NBKT];
    for (int i = threadIdx.x; i < NBKT; i += 256)
        cur[i] = off[i * ABLK + blockIdx.x];
    __syncthreads();
    int base = blockIdx.x * ECHUNK;
    for (int i = threadIdx.x; i < ECHUNK; i += 256) {
        int s = edges[base + i];
        int d = edges[N_EDGES + base + i];
        int p = atomicAdd(&cur[d >> 8], 1);  // LDS atomic only
        ebuf[p] = ((unsigned long long)(unsigned)d << 32) | (unsigned)s;
    }
}

// dst pass D: one block per bucket. Stage edges in LDS, count the bucket's
// 256 local nodes (dst&255), in-block scan -> row_ptr + fully grouped col.
__global__ void bucket_csr_kernel(const unsigned long long* __restrict__ ebuf,
                                  const int* __restrict__ off,
                                  int* __restrict__ row_ptr,
                                  int* __restrict__ col) {
    __shared__ unsigned long long eb[CAP_D];
    __shared__ int hist[256];
    __shared__ int sc[256];
    __shared__ int cur[256];
    const int b = blockIdx.x;
    const int tid = threadIdx.x;
    const int base = off[b * ABLK];
    const int end = (b == NBKT - 1) ? N_EDGES : off[(b + 1) * ABLK];
    const int count = end - base;
    hist[tid] = 0;
    __syncthreads();
    const bool inlds = (count <= CAP_D);
    for (int i = tid; i < count; i += 256) {
        unsigned long long ed = ebuf[base + i];
        if (inlds) eb[i] = ed;
        atomicAdd(&hist[(int)(ed >> 32) & 255], 1);
    }
    __syncthreads();
    int v = hist[tid];
    sc[tid] = v;
    __syncthreads();
    for (int o = 1; o < 256; o <<= 1) {
        int t = (tid >= o) ? sc[tid - o] : 0;
        __syncthreads();
        sc[tid] += t;
        __syncthreads();
    }
    int ex = sc[tid] - v;  // exclusive
    cur[tid] = ex;
    int node = b * 256 + tid;
    if (node <= N_NODES) row_ptr[node] = base + ex;  // covers row_ptr[N]==E
    __syncthreads();
    for (int i = tid; i < count; i += 256) {
        unsigned long long ed = inlds ? eb[i] : ebuf[base + i];
        int local = (int)(ed >> 32) & 255;
        int p = atomicAdd(&cur[local], 1);  // LDS atomic only
        col[base + p] = (int)(unsigned)ed;
    }
}

// src pass C: bare src values into bucket-ordered sbuf.
__global__ void src_scatter_kernel(const int* __restrict__ src,
                                   const int* __restrict__ off,
                                   int* __restrict__ sbuf) {
    __shared__ int cur[NBKT];
    for (int i = threadIdx.x; i < NBKT; i += 256)
        cur[i] = off[i * ABLK + blockIdx.x];
    __syncthreads();
    int base = blockIdx.x * ECHUNK;
    for (int i = threadIdx.x; i < ECHUNK; i += 256) {
        int s = src[base + i];
        int p = atomicAdd(&cur[s >> 8], 1);  // LDS atomic only
        sbuf[p] = s;
    }
}

// src pass D: per-bucket LDS histogram of low 8 bits -> outdeg (as float).
__global__ void src_hist_kernel(const int* __restrict__ sbuf,
                                const int* __restrict__ off,
                                float* __restrict__ outdegf) {
    __shared__ int hist[256];
    const int b = blockIdx.x;
    const int tid = threadIdx.x;
    hist[tid] = 0;
    __syncthreads();
    const int base = off[b * ABLK];
    const int end = (b == NBKT - 1) ? N_EDGES : off[(b + 1) * ABLK];
    for (int i = base + tid; i < end; i += 256)
        atomicAdd(&hist[sbuf[i] & 255], 1);
    __syncthreads();
    int node = b * 256 + tid;
    if (node < N_NODES) outdegf[node] = (float)hist[tid];
}

// ---- per-layer compute ----

// Atomic-free pull gather: wave-per-node, lane = feature.
__global__ void gather_kernel(const float* __restrict__ feat,
                              const int* __restrict__ row_ptr,
                              const int* __restrict__ col,
                              float* __restrict__ aggr) {
    int node = blockIdx.x * 4 + (threadIdx.x >> 6);
    int f = threadIdx.x & 63;
    if (node >= N_NODES) return;
    int beg = row_ptr[node];
    int end = row_ptr[node + 1];
    float acc = 0.f;
    int e = beg;
    for (; e + 3 < end; e += 4) {
        int s0 = col[e];
        int s1 = col[e + 1];
        int s2 = col[e + 2];
        int s3 = col[e + 3];
        float v0 = feat[(size_t)s0 * F + f];
        float v1 = feat[(size_t)s1 * F + f];
        float v2 = feat[(size_t)s2 * F + f];
        float v3 = feat[(size_t)s3 * F + f];
        acc += v0 + v1 + v2 + v3;
    }
    for (; e < end; e++) acc += feat[(size_t)col[e] * F + f];
    aggr[(size_t)node * F + f] = acc;
}

// Layer-1 transform: h1 = relu(aggr @ w_rel + b_rel + x @ w_root).
__global__ void transform_kernel(const float* __restrict__ aggr,
                                 const float* __restrict__ xin,
                                 const float* __restrict__ w_rel,
                                 const float* __restrict__ b_rel,
                                 const float* __restrict__ w_root,
                                 float* __restrict__ out) {
    __shared__ float sA[64 * F];
    __shared__ float sX[64 * F];
    const int node0 = blockIdx.x * 64;
    float4* s4A = (float4*)sA;
    float4* s4X = (float4*)sX;
    const float4* gA = (const float4*)(aggr + (size_t)node0 * F);
    const float4* gX = (const float4*)(xin + (size_t)node0 * F);
    for (int k = threadIdx.x; k < 64 * F / 4; k += 256) {
        int node = node0 + (k >> 4);
        float4 a = make_float4(0.f, 0.f, 0.f, 0.f);
        float4 x = a;
        if (node < N_NODES) { a = gA[k]; x = gX[k]; }
        s4A[k] = a;
        s4X[k] = x;
    }
    __syncthreads();

    const int fp = threadIdx.x & 63;
    const int grp = threadIdx.x >> 6;
    float acc[16];
    const float bias = b_rel[fp];
#pragma unroll
    for (int k = 0; k < 16; k++) acc[k] = bias;

    for (int f = 0; f < F; f += 4) {
        float wr0 = w_rel[(f + 0) * F + fp];
        float wr1 = w_rel[(f + 1) * F + fp];
        float wr2 = w_rel[(f + 2) * F + fp];
        float wr3 = w_rel[(f + 3) * F + fp];
        float wo0 = w_root[(f + 0) * F + fp];
        float wo1 = w_root[(f + 1) * F + fp];
        float wo2 = w_root[(f + 2) * F + fp];
        float wo3 = w_root[(f + 3) * F + fp];
#pragma unroll
        for (int k = 0; k < 16; k++) {
            int n = grp * 16 + k;
            float4 a = *(const float4*)&sA[n * F + f];
            float4 x = *(const float4*)&sX[n * F + f];
            acc[k] += a.x * wr0 + a.y * wr1 + a.z * wr2 + a.w * wr3
                    + x.x * wo0 + x.y * wo1 + x.z * wo2 + x.w * wo3;
        }
    }
#pragma unroll
    for (int k = 0; k < 16; k++) {
        int n = grp * 16 + k;
        int node = node0 + n;
        if (node < N_NODES)
            out[(size_t)node * F + fp] = fmaxf(acc[k], 0.0f);
    }
}

// Layer-2 transform FUSED with the collapsed layer-3 reduction:
//   h2 = relu(aggr @ w_rel2 + b2 + h1 @ w_root2)   (never written to global)
//   partial[blk][0:64]   = sum_{nodes in blk} outdeg(n) * h2[n][:]
//   partial[blk][64:128] = sum_{nodes in blk} h2[n][:]
__global__ void transform2_reduce_kernel(const float* __restrict__ aggr,
                                         const float* __restrict__ xin,
                                         const float* __restrict__ w_rel,
                                         const float* __restrict__ b_rel,
                                         const float* __restrict__ w_root,
                                         const float* __restrict__ outdegf,
                                         float* __restrict__ partial) {
    __shared__ float sA[64 * F];
    __shared__ float sX[64 * F];
    __shared__ float sD[64];
    __shared__ float sR[512];
    const int node0 = blockIdx.x * 64;
    float4* s4A = (float4*)sA;
    float4* s4X = (float4*)sX;
    const float4* gA = (const float4*)(aggr + (size_t)node0 * F);
    const float4* gX = (const float4*)(xin + (size_t)node0 * F);
    for (int k = threadIdx.x; k < 64 * F / 4; k += 256) {
        int node = node0 + (k >> 4);
        float4 a = make_float4(0.f, 0.f, 0.f, 0.f);
        float4 x = a;
        if (node < N_NODES) { a = gA[k]; x = gX[k]; }
        s4A[k] = a;
        s4X[k] = x;
    }
    if (threadIdx.x < 64) {
        int node = node0 + threadIdx.x;
        sD[threadIdx.x] = (node < N_NODES) ? outdegf[node] : 0.f;
    }
    __syncthreads();

    const int fp = threadIdx.x & 63;
    const int grp = threadIdx.x >> 6;
    float acc[16];
    const float bias = b_rel[fp];
#pragma unroll
    for (int k = 0; k < 16; k++) acc[k] = bias;

    for (int f = 0; f < F; f += 4) {
        float wr0 = w_rel[(f + 0) * F + fp];
        float wr1 = w_rel[(f + 1) * F + fp];
        float wr2 = w_rel[(f + 2) * F + fp];
        float wr3 = w_rel[(f + 3) * F + fp];
        float wo0 = w_root[(f + 0) * F + fp];
        float wo1 = w_root[(f + 1) * F + fp];
        float wo2 = w_root[(f + 2) * F + fp];
        float wo3 = w_root[(f + 3) * F + fp];
#pragma unroll
        for (int k = 0; k < 16; k++) {
            int n = grp * 16 + k;
            float4 a = *(const float4*)&sA[n * F + f];
            float4 x = *(const float4*)&sX[n * F + f];
            acc[k] += a.x * wr0 + a.y * wr1 + a.z * wr2 + a.w * wr3
                    + x.x * wo0 + x.y * wo1 + x.z * wo2 + x.w * wo3;
        }
    }

    float s1 = 0.f, s2 = 0.f;
#pragma unroll
    for (int k = 0; k < 16; k++) {
        int n = grp * 16 + k;
        int node = node0 + n;
        if (node < N_NODES) {
            float v = fmaxf(acc[k], 0.0f);
            s1 += sD[n] * v;
            s2 += v;
        }
    }
    sR[threadIdx.x] = s1;
    sR[256 + threadIdx.x] = s2;
    __syncthreads();
    if (threadIdx.x < 64) {
        int t = threadIdx.x;
        float t1 = sR[t] + sR[64 + t] + sR[128 + t] + sR[192 + t];
        float t2 = sR[256 + t] + sR[320 + t] + sR[384 + t] + sR[448 + t];
        partial[(size_t)blockIdx.x * 128 + t] = t1;
        partial[(size_t)blockIdx.x * 128 + 64 + t] = t2;
    }
}

// out = (S1 . w_rel3 + S2 . w_root3)/N + b3, S from 1563x128 partials.
__global__ void final_reduce_kernel(const float* __restrict__ partial,
                                    const float* __restrict__ w_rel3,
                                    const float* __restrict__ b_rel3,
                                    const float* __restrict__ w_root3,
                                    float* __restrict__ out) {
    __shared__ float sS[1024];
    __shared__ float sT[128];
    const int t = threadIdx.x;           // 1024 threads
    const int f = t & 127;
    const int g = t >> 7;                // 8 interleaved groups
    float s = 0.f;
    for (int k = g; k < TBLK; k += 8) s += partial[(size_t)k * 128 + f];
    sS[t] = s;
    __syncthreads();
    if (t < 128) {
        float tot = 0.f;
#pragma unroll
        for (int j = 0; j < 8; j++) tot += sS[j * 128 + t];
        sT[t] = tot;
    }
    __syncthreads();
    if (t < 64) {
        float v = sT[t] * w_rel3[t] + sT[64 + t] * w_root3[t];
        for (int off = 32; off > 0; off >>= 1) v += __shfl_down(v, off);
        if (t == 0) out[0] = v * (1.0f / (float)N_NODES) + b_rel3[0];
    }
}

extern "C" void kernel_launch(void* const* d_in, const int* in_sizes, int n_in,
                              void* d_out, int out_size, void* d_ws, size_t ws_size,
                              hipStream_t stream) {
    const float* x       = (const float*)d_in[0];
    const int*   edges   = (const int*)d_in[1];   // [2, E]: src row then dst row
    const float* w_rel1  = (const float*)d_in[2];
    const float* b_rel1  = (const float*)d_in[3];
    const float* w_root1 = (const float*)d_in[4];
    const float* w_rel2  = (const float*)d_in[5];
    const float* b_rel2  = (const float*)d_in[6];
    const float* w_root2 = (const float*)d_in[7];
    const float* w_rel3  = (const float*)d_in[8];
    const float* b_rel3  = (const float*)d_in[9];
    const float* w_root3 = (const float*)d_in[10];
    float* out = (float*)d_out;

    const size_t nf = (size_t)N_NODES * F;
    float* aggr    = (float*)d_ws;                 // 25.6 MB
    float* h1      = aggr + nf;                    // 25.6 MB
    int*   row_ptr = (int*)(h1 + nf);              // 400 KB
    int*   col     = row_ptr + N_NODES + 1;        // 6.4 MB
    int*   cnt     = col + N_EDGES;                // 400 KB (dst pass, then src pass)
    int*   off     = cnt + M_CNT;                  // 400 KB (dst pass, then src pass)
    int*   bsum2   = off + M_CNT;                  // ~1 KB
    int*   boff2   = bsum2 + S2B;                  // ~1 KB
    float* outdegf = (float*)(boff2 + S2B);        // 400 KB
    float* partial = outdegf + N_NODES;            // 800 KB
    // overlays inside aggr (dead until the first gather writes it):
    unsigned long long* ebuf = (unsigned long long*)aggr;        // 12.8 MB
    int* sbuf = (int*)(aggr + 2 * (size_t)N_EDGES);              // 6.4 MB

    const int* src_row = edges;
    const int* dst_row = edges + N_EDGES;

    // ---- dst counting sort -> CSR (row_ptr, col); no global atomics ----
    bucket_count_kernel<<<ABLK, 256, 0, stream>>>(dst_row, cnt);
    s_bsum<<<S2B, 256, 0, stream>>>(cnt, M_CNT, bsum2);
    s_bscan<<<1, 256, 0, stream>>>(bsum2, S2B, boff2);
    s_scan_write<<<S2B, 256, 0, stream>>>(cnt, M_CNT, boff2, off);
    bucket_scatter_kernel<<<ABLK, 256, 0, stream>>>(edges, off, ebuf);
    bucket_csr_kernel<<<NBKT, 256, 0, stream>>>(ebuf, off, row_ptr, col);

    // ---- src counting pass -> outdegf (reuses cnt/off; no global atomics) ----
    bucket_count_kernel<<<ABLK, 256, 0, stream>>>(src_row, cnt);
    s_bsum<<<S2B, 256, 0, stream>>>(cnt, M_CNT, bsum2);
    s_bscan<<<1, 256, 0, stream>>>(bsum2, S2B, boff2);
    s_scan_write<<<S2B, 256, 0, stream>>>(cnt, M_CNT, boff2, off);
    src_scatter_kernel<<<ABLK, 256, 0, stream>>>(src_row, off, sbuf);
    src_hist_kernel<<<NBKT, 256, 0, stream>>>(sbuf, off, outdegf);

    const int gather_blocks = (N_NODES + 3) / 4;

    // layer 1 (gather overwrites the ebuf/sbuf overlays — they're dead now)
    gather_kernel<<<gather_blocks, 256, 0, stream>>>(x, row_ptr, col, aggr);
    transform_kernel<<<TBLK, 256, 0, stream>>>(aggr, x, w_rel1, b_rel1, w_root1, h1);

    // layer 2 + collapsed layer 3 (h2 never materialized)
    gather_kernel<<<gather_blocks, 256, 0, stream>>>(h1, row_ptr, col, aggr);
    transform2_reduce_kernel<<<TBLK, 256, 0, stream>>>(aggr, h1, w_rel2, b_rel2,
                                                       w_root2, outdegf, partial);
    final_reduce_kernel<<<1, 1024, 0, stream>>>(partial, w_rel3, b_rel3, w_root3, out);
}